// Round 7
// baseline (149.248 us; speedup 1.0000x reference)
//
#include <hip/hip_runtime.h>
#include <stdint.h>
#include <stddef.h>

typedef _Float16 f16;
typedef f16 f16x4 __attribute__((ext_vector_type(4)));
typedef f16 f16x8 __attribute__((ext_vector_type(8)));
typedef float f32x4 __attribute__((ext_vector_type(4)));
typedef int ix16 __attribute__((ext_vector_type(16)));

#define DEV __device__ __forceinline__

constexpr int Bb = 4, Nn = 8192, Mm = 2048, C1 = 128, C2 = 256;
constexpr int K0 = 384, CO = 256;

// ---------------------------------------------------------------- 1) fused prep: kfT transpose (z<4) + weight repack (z==4) + k4 pack (z==5)
__global__ __launch_bounds__(256) void prep_kernel(
    const float* __restrict__ kf, f16* __restrict__ kfT,
    const float* __restrict__ W0, const float* __restrict__ W1,
    f16* __restrict__ Af0, f16* __restrict__ Af1,
    const float* __restrict__ known, float4* __restrict__ k4)
{
  const int t = threadIdx.x;
  if (blockIdx.z < 4) {
    // known_feats (B,C2,M) f32 -> kfT (B,M,C2) f16
    __shared__ f16 tile[64][72];
    const int m0 = blockIdx.x * 64, c0 = blockIdx.y * 64, b = blockIdx.z;
    const int lm = t & 63, row = t >> 6;
#pragma unroll
    for (int j = 0; j < 16; ++j) {
      int c = row + j * 4;
      tile[lm][c] = (f16)kf[(size_t)(b * C2 + c0 + c) * Mm + m0 + lm];
    }
    __syncthreads();
#pragma unroll
    for (int j = 0; j < 16; ++j) {
      int m = row + j * 4;
      kfT[(size_t)(b * Mm + m0 + m) * C2 + c0 + lm] = tile[m][lm];
    }
  } else if (blockIdx.z == 4) {
    // weights f32 -> f16 in MFMA A-fragment order; 128 blocks x 256 thr x 3 iters = 98304 ids
    const int bid = blockIdx.y * 32 + blockIdx.x;
#pragma unroll
    for (int r = 0; r < 3; ++r) {
      int id = bid * 256 + t + r * 32768;
      int e = id & 7, lane = (id >> 3) & 63, mg = (id >> 9) & 15, ks = id >> 13;
      int m = mg * 16 + (lane & 15), k = ks * 32 + (lane >> 4) * 8 + e;
      if (id < CO * K0) Af0[id] = (f16)W0[m * K0 + k];
      if (id < CO * CO) Af1[id] = (f16)W1[m * CO + k];
    }
  } else {
    // known (B,M,3) f32 -> k4 (B*M) float4 (kx,ky,kz,kk); kk np-exact chain
    int id = (blockIdx.y * 32 + blockIdx.x) * 256 + t;
    if (id < Bb * Mm) {
      float kx = known[id * 3 + 0];
      float ky = known[id * 3 + 1];
      float kz = known[id * 3 + 2];
      float kk = __fadd_rn(__fadd_rn(__fmul_rn(kx, kx), __fmul_rn(ky, ky)), __fmul_rn(kz, kz));
      k4[id] = make_float4(kx, ky, kz, kk);
    }
  }
}

// ---------------------------------------------------------------- 2) fully fused: three_nn + interp + concat + MLP0 + MLP1
// Phase A streams candidates through SGPRs: each wave s_load_dwordx16's its wave-uniform
// 256-cand slice of k4 (4 cands/load, 8-cand double-buffered groups, rolled loop with SGPR
// offset). No LDS staging, no ds_read in the scan, no pre-scan barrier — the candidate was
// always wave-uniform and never needed the vector memory path. SMEM returns are unordered ->
// only lgkmcnt(0) waits, each covered by the preceding 8-STEP (~300 cyc) consume block.
// Per-pair math+selection is the verified 19-instr asm STEP with candidate operands in SGPRs
// (each VALU reads <=1 non-vcc SGPR; mul/add operands commuted — bitwise identical chain:
// dot2 = fl(fl(fl(kx*ux2)+fl(ky*uy2))+fl(kz*uz2)), dd = fl(kk+fl(uu-dot2)); strict-less
// insert, increasing gm). Partition = R5's verified 8 waves x 256 cands; (d,i)-lex merge.
// Phase B: R5's verified body (64-query tile, acc[2][4], kg=wave interp).
__global__ __launch_bounds__(512, 4) void fused_kernel(
    const float* __restrict__ unknown, const float4* __restrict__ k4,
    const f16* __restrict__ Af0, const f16* __restrict__ Af1,
    const f16* __restrict__ kfT, const float* __restrict__ uf,
    const float* __restrict__ bs0, const float* __restrict__ g0,
    const float* __restrict__ be0, const float* __restrict__ rm0, const float* __restrict__ rv0,
    const float* __restrict__ bs1, const float* __restrict__ g1,
    const float* __restrict__ be1, const float* __restrict__ rm1, const float* __restrict__ rv1,
    float* __restrict__ out)
{
  __shared__ __align__(16) char lds[54784];
  // [0,49152)      phase A: merge arrays (12KB); phase B: B-tile (48KB)
  // [49152,53248)  bn tables (4 x 1KB)
  // [53248,54016)  idxR[64][3] i32
  // [54016,54784)  wR[64][3] f32
  float* mergeD = (float*)lds;                 // [8][64][3] f32 = 6 KB
  int*   mergeI = (int*)(lds + 6144);          // [8][64][3] i32 = 6 KB
  float* bn0S = (float*)(lds + 49152);
  float* bn0H = (float*)(lds + 50176);
  float* bn1S = (float*)(lds + 51200);
  float* bn1H = (float*)(lds + 52224);
  int*   idxR = (int*)(lds + 53248);
  float* wR   = (float*)(lds + 54016);

  const int t = threadIdx.x;
  const int l = t & 63;
  const int w = __builtin_amdgcn_readfirstlane(t >> 6);   // wave id 0..7 (scalar)
  const int gid = blockIdx.x;
  const int b = gid >> 7, n0 = (gid & 127) * 64;

  // bn tables (disjoint LDS region)
  if (t < 256) {
    float sc0 = g0[t] / sqrtf(rv0[t] + 1e-5f);
    bn0S[t] = sc0; bn0H[t] = (bs0[t] - rm0[t]) * sc0 + be0[t];
    float sc1 = g1[t] / sqrtf(rv1[t] + 1e-5f);
    bn1S[t] = sc1; bn1H[t] = (bs1[t] - rm1[t]) * sc1 + be1[t];
  }

  {
    const int q = n0 + l;
    float ux = unknown[(b * Nn + q) * 3 + 0];
    float uy = unknown[(b * Nn + q) * 3 + 1];
    float uz = unknown[(b * Nn + q) * 3 + 2];
    float uu = __fadd_rn(__fadd_rn(__fmul_rn(ux, ux), __fmul_rn(uy, uy)), __fmul_rn(uz, uz));
    float ux2 = ux + ux, uy2 = uy + uy, uz2 = uz + uz;   // exact (x2 = exponent bump)

    const float4* kb4 = k4 + (size_t)b * Mm + (w << 8);  // wave-uniform slice base (SGPR pair)

    float d1 = 1e30f, d2 = 1e30f, d3 = 1e30f;
    int   i1 = 0, i2 = 0, i3 = 0;
    int   gmv = w << 8;                  // running candidate index (VGPR, +1 per STEP)
    float tmp0, tmp1;
    uint64_t q1m, q2m;

    // 19-instr STEP, candidates in SGPRs (each VALU reads <=1 non-vcc SGPR).
#define STEPS(kx_, ky_, kz_, kk_) \
  asm volatile( \
    "v_mul_f32 %[t], %[kx], %[ux2]\n\t" \
    "v_mul_f32 %[s], %[ky], %[uy2]\n\t" \
    "v_add_f32 %[t], %[t], %[s]\n\t" \
    "v_mul_f32 %[s], %[kz], %[uz2]\n\t" \
    "v_add_f32 %[t], %[t], %[s]\n\t" \
    "v_sub_f32 %[t], %[uu], %[t]\n\t" \
    "v_add_f32 %[t], %[kk], %[t]\n\t" \
    "v_cmp_lt_f32 %[q1], %[t], %[d1]\n\t" \
    "v_cmp_lt_f32 %[q2], %[t], %[d2]\n\t" \
    "v_cmp_lt_f32 vcc, %[t], %[d3]\n\t" \
    "v_med3_f32 %[d3], %[t], %[d2], %[d3]\n\t" \
    "v_med3_f32 %[d2], %[t], %[d1], %[d2]\n\t" \
    "v_min_f32 %[d1], %[t], %[d1]\n\t" \
    "v_cndmask_b32 %[s], %[gm], %[i2], %[q2]\n\t" \
    "v_cndmask_b32 %[i3], %[i3], %[s], vcc\n\t" \
    "v_cndmask_b32 %[s], %[gm], %[i1], %[q1]\n\t" \
    "v_cndmask_b32 %[i2], %[i2], %[s], %[q2]\n\t" \
    "v_cndmask_b32 %[i1], %[i1], %[gm], %[q1]\n\t" \
    "v_add_u32 %[gm], 1, %[gm]\n\t" \
    : [d1]"+v"(d1), [d2]"+v"(d2), [d3]"+v"(d3), \
      [i1]"+v"(i1), [i2]"+v"(i2), [i3]"+v"(i3), \
      [gm]"+v"(gmv), [t]"=&v"(tmp0), [s]"=&v"(tmp1), \
      [q1]"=&s"(q1m), [q2]"=&s"(q2m) \
    : [ux2]"v"(ux2), [uy2]"v"(uy2), [uz2]"v"(uz2), [uu]"v"(uu), \
      [kx]"s"(kx_), [ky]"s"(ky_), [kz]"s"(kz_), [kk]"s"(kk_) \
    : "vcc")

#define SLOAD2(B0_, B1_, OFF_) \
  asm volatile("s_load_dwordx16 %0, %2, %3\n\t" \
               "s_load_dwordx16 %1, %2, %4" \
               : "=&s"(B0_), "=&s"(B1_) : "s"(kb4), "s"(OFF_), "s"((OFF_) + 64))
#define SWAIT() asm volatile("s_waitcnt lgkmcnt(0)")
#define CONS(L_, H_) \
  STEPS(__int_as_float((L_)[0]),  __int_as_float((L_)[1]),  __int_as_float((L_)[2]),  __int_as_float((L_)[3]));  \
  STEPS(__int_as_float((L_)[4]),  __int_as_float((L_)[5]),  __int_as_float((L_)[6]),  __int_as_float((L_)[7]));  \
  STEPS(__int_as_float((L_)[8]),  __int_as_float((L_)[9]),  __int_as_float((L_)[10]), __int_as_float((L_)[11])); \
  STEPS(__int_as_float((L_)[12]), __int_as_float((L_)[13]), __int_as_float((L_)[14]), __int_as_float((L_)[15])); \
  STEPS(__int_as_float((H_)[0]),  __int_as_float((H_)[1]),  __int_as_float((H_)[2]),  __int_as_float((H_)[3]));  \
  STEPS(__int_as_float((H_)[4]),  __int_as_float((H_)[5]),  __int_as_float((H_)[6]),  __int_as_float((H_)[7]));  \
  STEPS(__int_as_float((H_)[8]),  __int_as_float((H_)[9]),  __int_as_float((H_)[10]), __int_as_float((H_)[11])); \
  STEPS(__int_as_float((H_)[12]), __int_as_float((H_)[13]), __int_as_float((H_)[14]), __int_as_float((H_)[15]))

    ix16 A0, A1, B0, B1;
    uint32_t off = 0;
    SLOAD2(A0, A1, off); off += 128;
    for (int g = 0; g < 15; ++g) {       // 2 groups (16 cands) per iteration
      SWAIT(); SLOAD2(B0, B1, off); off += 128;
      CONS(A0, A1);
      SWAIT(); SLOAD2(A0, A1, off); off += 128;
      CONS(B0, B1);
    }
    SWAIT(); SLOAD2(B0, B1, off);
    CONS(A0, A1);
    SWAIT();
    CONS(B0, B1);
#undef STEPS
#undef SLOAD2
#undef SWAIT
#undef CONS

    // ---- per-wave partials -> LDS, wave 0 merges (ties -> lower index)
    mergeD[(w * 64 + l) * 3 + 0] = d1; mergeD[(w * 64 + l) * 3 + 1] = d2; mergeD[(w * 64 + l) * 3 + 2] = d3;
    mergeI[(w * 64 + l) * 3 + 0] = i1; mergeI[(w * 64 + l) * 3 + 1] = i2; mergeI[(w * 64 + l) * 3 + 2] = i3;
    __syncthreads();

    if (t < 64) {
      d1 = mergeD[t * 3 + 0]; d2 = mergeD[t * 3 + 1]; d3 = mergeD[t * 3 + 2];
      i1 = mergeI[t * 3 + 0]; i2 = mergeI[t * 3 + 1]; i3 = mergeI[t * 3 + 2];
#pragma unroll
      for (int ww = 1; ww < 8; ++ww) {
#pragma unroll
        for (int u = 0; u < 3; ++u) {
          float e = mergeD[(ww * 64 + t) * 3 + u];
          int   j = mergeI[(ww * 64 + t) * 3 + u];
          bool c3 = (e < d3) || (e == d3 && j < i3);
          bool c2 = (e < d2) || (e == d2 && j < i2);
          bool c1 = (e < d1) || (e == d1 && j < i1);
          d3 = c3 ? (c2 ? d2 : e) : d3;  i3 = c3 ? (c2 ? i2 : j) : i3;
          d2 = c2 ? (c1 ? d1 : e) : d2;  i2 = c2 ? (c1 ? i1 : j) : i2;
          d1 = c1 ? e : d1;              i1 = c1 ? j : i1;
        }
      }
      float t1 = sqrtf(fmaxf(d1, 0.f)), t2 = sqrtf(fmaxf(d2, 0.f)), t3 = sqrtf(fmaxf(d3, 0.f));
      float r1 = 1.f / (t1 + 1e-8f), r2 = 1.f / (t2 + 1e-8f), r3 = 1.f / (t3 + 1e-8f);
      float rs = __fadd_rn(__fadd_rn(r1, r2), r3);
      idxR[t * 3 + 0] = i1; idxR[t * 3 + 1] = i2; idxR[t * 3 + 2] = i3;
      wR[t * 3 + 0] = r1 / rs; wR[t * 3 + 1] = r2 / rs; wR[t * 3 + 2] = r3 / rs;
    }
  }
  __syncthreads();

  // ---------------- phase B: interp + concat + MLP0 + MLP1 (R5 verified body, idx/wts from LDS)
  const int lm = l & 15, qq = l >> 4;

  {
    // kg = wave id (wave-uniform), n = lane -> simultaneous lanes differ in n; ^(n&7)
    // swizzle spreads banks.
    const int n = l, kg = w;
    int i0 = idxR[n * 3 + 0], i1 = idxR[n * 3 + 1], i2 = idxR[n * 3 + 2];
    float w0 = wR[n * 3 + 0], w1 = wR[n * 3 + 1], w2 = wR[n * 3 + 2];
    f16 w0h = (f16)w0, w1h = (f16)w1, w2h = (f16)w2;
    f16x8 w0v = {w0h, w0h, w0h, w0h, w0h, w0h, w0h, w0h};
    f16x8 w1v = {w1h, w1h, w1h, w1h, w1h, w1h, w1h, w1h};
    f16x8 w2v = {w2h, w2h, w2h, w2h, w2h, w2h, w2h, w2h};
    const f16x8* r0 = (const f16x8*)(kfT + (size_t)(b * Mm + i0) * C2 + kg * 32);
    const f16x8* r1 = (const f16x8*)(kfT + (size_t)(b * Mm + i1) * C2 + kg * 32);
    const f16x8* r2 = (const f16x8*)(kfT + (size_t)(b * Mm + i2) * C2 + kg * 32);
#pragma unroll
    for (int j = 0; j < 4; ++j) {
      f16x8 o = r0[j] * w0v + r1[j] * w1v + r2[j] * w2v;
      int oct = kg * 4 + j;
      *(f16x8*)(lds + n * 768 + ((oct ^ (n & 7)) * 16)) = o;
    }
  }
  {
    const int n = l, cb = w * 16;
    const float* src = uf + (size_t)(b * C1 + cb) * Nn + n0 + n;
#pragma unroll
    for (int jj = 0; jj < 2; ++jj) {
      f16x8 v;
#pragma unroll
      for (int e = 0; e < 8; ++e) v[e] = (f16)src[(size_t)(jj * 8 + e) * Nn];
      int oct = 32 + w * 2 + jj;
      *(f16x8*)(lds + n * 768 + ((oct ^ (n & 7)) * 16)) = v;
    }
  }
  __syncthreads();

  f32x4 acc[2][4] = {};
  {
    f16x8 af[2];
#pragma unroll
    for (int i = 0; i < 2; ++i)
      af[i] = *(const f16x8*)(Af0 + ((size_t)(w * 2 + i) * 64 + l) * 8);
    for (int ks = 0; ks < 12; ++ks) {
      f16x8 afn[2];
      if (ks < 11) {
#pragma unroll
        for (int i = 0; i < 2; ++i)
          afn[i] = *(const f16x8*)(Af0 + ((size_t)((ks + 1) * 16 + w * 2 + i) * 64 + l) * 8);
      }
      f16x8 bf[4];
#pragma unroll
      for (int j = 0; j < 4; ++j) {
        int n = j * 16 + lm;
        bf[j] = *(const f16x8*)(lds + n * 768 + (((ks * 4 + qq) ^ (n & 7)) * 16));
      }
#pragma unroll
      for (int i = 0; i < 2; ++i)
#pragma unroll
        for (int j = 0; j < 4; ++j)
          acc[i][j] = __builtin_amdgcn_mfma_f32_16x16x32_f16(af[i], bf[j], acc[i][j], 0, 0, 0);
#pragma unroll
      for (int i = 0; i < 2; ++i) af[i] = afn[i];
    }
  }
  __syncthreads();

#pragma unroll
  for (int i = 0; i < 2; ++i) {
    const int mq = w * 32 + i * 16 + qq * 4;
    f32x4 s4 = *(const f32x4*)&bn0S[mq];
    f32x4 h4 = *(const f32x4*)&bn0H[mq];
#pragma unroll
    for (int j = 0; j < 4; ++j) {
      int n = j * 16 + lm;
      f16x4 v;
#pragma unroll
      for (int r = 0; r < 4; ++r) v[r] = (f16)fmaxf(fmaf(acc[i][j][r], s4[r], h4[r]), 0.f);
      *(f16x4*)(lds + n * 512 + (((mq >> 3) ^ (n & 7)) * 16) + (mq & 7) * 2) = v;
    }
  }
  __syncthreads();

#pragma unroll
  for (int i = 0; i < 2; ++i)
#pragma unroll
    for (int j = 0; j < 4; ++j) acc[i][j] = f32x4{0.f, 0.f, 0.f, 0.f};
  {
    f16x8 af[2];
#pragma unroll
    for (int i = 0; i < 2; ++i)
      af[i] = *(const f16x8*)(Af1 + ((size_t)(w * 2 + i) * 64 + l) * 8);
    for (int ks = 0; ks < 8; ++ks) {
      f16x8 afn[2];
      if (ks < 7) {
#pragma unroll
        for (int i = 0; i < 2; ++i)
          afn[i] = *(const f16x8*)(Af1 + ((size_t)((ks + 1) * 16 + w * 2 + i) * 64 + l) * 8);
      }
      f16x8 bf[4];
#pragma unroll
      for (int j = 0; j < 4; ++j) {
        int n = j * 16 + lm;
        bf[j] = *(const f16x8*)(lds + n * 512 + (((ks * 4 + qq) ^ (n & 7)) * 16));
      }
#pragma unroll
      for (int i = 0; i < 2; ++i)
#pragma unroll
        for (int j = 0; j < 4; ++j)
          acc[i][j] = __builtin_amdgcn_mfma_f32_16x16x32_f16(af[i], bf[j], acc[i][j], 0, 0, 0);
#pragma unroll
      for (int i = 0; i < 2; ++i) af[i] = afn[i];
    }
  }

#pragma unroll
  for (int i = 0; i < 2; ++i) {
    const int mq = w * 32 + i * 16 + qq * 4;
    f32x4 s4 = *(const f32x4*)&bn1S[mq];
    f32x4 h4 = *(const f32x4*)&bn1H[mq];
#pragma unroll
    for (int r = 0; r < 4; ++r) {
      const int m = mq + r;
#pragma unroll
      for (int j = 0; j < 4; ++j) {
        int n = j * 16 + lm;
        out[(size_t)(b * CO + m) * Nn + n0 + n] = fmaxf(fmaf(acc[i][j][r], s4[r], h4[r]), 0.f);
      }
    }
  }
}

// ---------------------------------------------------------------- launch
extern "C" void kernel_launch(void* const* d_in, const int* in_sizes, int n_in,
                              void* d_out, int out_size, void* d_ws, size_t ws_size,
                              hipStream_t stream)
{
  const float* unknown = (const float*)d_in[0];
  const float* known   = (const float*)d_in[1];
  const float* uf      = (const float*)d_in[2];
  const float* kf      = (const float*)d_in[3];
  const float* W0  = (const float*)d_in[4];
  const float* b0  = (const float*)d_in[5];
  const float* g0  = (const float*)d_in[6];
  const float* be0 = (const float*)d_in[7];
  const float* rm0 = (const float*)d_in[8];
  const float* rv0 = (const float*)d_in[9];
  const float* W1  = (const float*)d_in[10];
  const float* b1  = (const float*)d_in[11];
  const float* g1  = (const float*)d_in[12];
  const float* be1 = (const float*)d_in[13];
  const float* rm1 = (const float*)d_in[14];
  const float* rv1 = (const float*)d_in[15];

  char* ws = (char*)d_ws;
  f16*    kfT = (f16*)   (ws + 0);          // B*M*C2 f16 = 4 MB
  f16*    Af0 = (f16*)   (ws + 4194304);    // 256*384 f16 (fragment-order)
  f16*    Af1 = (f16*)   (ws + 4390912);    // 256*256 f16 (fragment-order)
  float4* k4  = (float4*)(ws + 4521984);    // B*M float4 (kx,ky,kz,kk) = 128 KB
  float*  out = (float*)d_out;              // (B,256,N) f32

  prep_kernel <<<dim3(32, 4, 6), 256, 0, stream>>>(kf, kfT, W0, W1, Af0, Af1, known, k4);
  fused_kernel<<<dim3(Bb * (Nn / 64)), 512, 0, stream>>>(
      unknown, k4, Af0, Af1, kfT, uf,
      b0, g0, be0, rm0, rv0, b1, g1, be1, rm1, rv1, out);
}